// Round 8
// baseline (2225.310 us; speedup 1.0000x reference)
//
#include <hip/hip_runtime.h>
#include <hip/hip_bf16.h>
#include <cstdint>
#include <cstddef>

#define DEV __device__ __forceinline__

typedef __attribute__((ext_vector_type(8))) short short8;   // 8 bf16 (4 VGPR)
typedef __attribute__((ext_vector_type(4))) short s16x4;
typedef __attribute__((ext_vector_type(4))) float f32x4;
typedef unsigned short u16;
typedef unsigned int u32;

static constexpr int Vv = 50257;
static constexpr int Dd = 768;
static constexpr int Ll = 12;
static constexpr int Hh = 12;
static constexpr int Ff = 3072;
static constexpr int Ss = 1024;
static constexpr int Bbatch = 2;
static constexpr int DHh = 64;
static constexpr int Mtok = Bbatch * Ss;   // 2048
static constexpr int NQKV = 3 * Dd;        // 2304
static constexpr int VPAD = 50304;         // 50257 padded to 128-multiple

DEV u16 f2bf(float f){ u32 x; __builtin_memcpy(&x, &f, 4); x += 0x7fffu + ((x >> 16) & 1u); return (u16)(x >> 16); }

DEV void gld_lds16(const void* g, void* l){
  __builtin_amdgcn_global_load_lds((const __attribute__((address_space(1))) void*)g,
                                   (__attribute__((address_space(3))) void*)l, 16, 0, 0);
}

template<int N> DEV void waitv(){
  if constexpr (N == 0) asm volatile("s_waitcnt vmcnt(0)" ::: "memory");
  else if constexpr (N == 2) asm volatile("s_waitcnt vmcnt(2)" ::: "memory");
  else if constexpr (N == 3) asm volatile("s_waitcnt vmcnt(3)" ::: "memory");
  else if constexpr (N == 4) asm volatile("s_waitcnt vmcnt(4)" ::: "memory");
  else if constexpr (N == 6) asm volatile("s_waitcnt vmcnt(6)" ::: "memory");
  else if constexpr (N == 8) asm volatile("s_waitcnt vmcnt(8)" ::: "memory");
}
DEV void barrier_sb(){
  __builtin_amdgcn_s_barrier();
  __builtin_amdgcn_sched_barrier(0);
}

// ---------------- fused embedding + LN1(layer0): f32 x out, bf16 h out ----------------
__global__ __launch_bounds__(256) void k_embed_ln(const int* __restrict__ ids, const float* __restrict__ tok,
                                                  const float* __restrict__ pos, const float* __restrict__ g,
                                                  const float* __restrict__ b, float* __restrict__ x,
                                                  u16* __restrict__ h){
  int t = blockIdx.x, tid = threadIdx.x;
  int id = ids[t];
  int s = t & (Ss - 1);
  const float* tr = tok + (size_t)id * Dd;
  const float* pr = pos + (size_t)s * Dd;
  float v0 = tr[tid] + pr[tid], v1 = tr[tid + 256] + pr[tid + 256], v2 = tr[tid + 512] + pr[tid + 512];
  float* xr = x + (size_t)t * Dd;
  xr[tid] = v0; xr[tid + 256] = v1; xr[tid + 512] = v2;
  float sm = v0 + v1 + v2, ss = v0 * v0 + v1 * v1 + v2 * v2;
  for (int o = 1; o < 64; o <<= 1){ sm += __shfl_xor(sm, o, 64); ss += __shfl_xor(ss, o, 64); }
  __shared__ float red[8];
  int w = tid >> 6, l = tid & 63;
  if (l == 0){ red[w] = sm; red[w + 4] = ss; }
  __syncthreads();
  sm = red[0] + red[1] + red[2] + red[3];
  ss = red[4] + red[5] + red[6] + red[7];
  float mu = sm * (1.0f / Dd);
  float var = ss * (1.0f / Dd) - mu * mu;
  float rs = rsqrtf(var + 1e-5f);
  u16* yr = h + (size_t)t * Dd;
  yr[tid]       = f2bf((v0 - mu) * rs * g[tid]       + b[tid]);
  yr[tid + 256] = f2bf((v1 - mu) * rs * g[tid + 256] + b[tid + 256]);
  yr[tid + 512] = f2bf((v2 - mu) * rs * g[tid + 512] + b[tid + 512]);
}

// ---------------- layernorm: f32 in -> bf16 out ----------------
__global__ __launch_bounds__(256) void k_ln(const float* __restrict__ x, const float* __restrict__ g,
                                            const float* __restrict__ b, u16* __restrict__ y){
  int row = blockIdx.x, tid = threadIdx.x;
  const float* xr = x + (size_t)row * Dd;
  float v0 = xr[tid], v1 = xr[tid + 256], v2 = xr[tid + 512];
  float s = v0 + v1 + v2, ss = v0 * v0 + v1 * v1 + v2 * v2;
  for (int o = 1; o < 64; o <<= 1){ s += __shfl_xor(s, o, 64); ss += __shfl_xor(ss, o, 64); }
  __shared__ float red[8];
  int w = tid >> 6, l = tid & 63;
  if (l == 0){ red[w] = s; red[w + 4] = ss; }
  __syncthreads();
  s = red[0] + red[1] + red[2] + red[3];
  ss = red[4] + red[5] + red[6] + red[7];
  float mu = s * (1.0f / Dd);
  float var = ss * (1.0f / Dd) - mu * mu;
  float rs = rsqrtf(var + 1e-5f);
  u16* yr = y + (size_t)row * Dd;
  yr[tid]       = f2bf((v0 - mu) * rs * g[tid]       + b[tid]);
  yr[tid + 256] = f2bf((v1 - mu) * rs * g[tid + 256] + b[tid + 256]);
  yr[tid + 512] = f2bf((v2 - mu) * rs * g[tid + 512] + b[tid + 512]);
}

// ---------------- fused: combine 2 split-K partials + bias + residual -> x, then LN -> h ----------------
__global__ __launch_bounds__(256) void k_combineln(const float* __restrict__ p, const float* __restrict__ bias,
                                                   float* __restrict__ x, const float* __restrict__ g,
                                                   const float* __restrict__ b, u16* __restrict__ h){
  constexpr size_t SL = (size_t)Mtok * Dd;
  int row = blockIdx.x, tid = threadIdx.x;
  float* xr = x + (size_t)row * Dd;
  const float* p0 = p + (size_t)row * Dd;
  const float* p1 = p0 + SL;
  float v0 = xr[tid]       + p0[tid]       + p1[tid]       + bias[tid];
  float v1 = xr[tid + 256] + p0[tid + 256] + p1[tid + 256] + bias[tid + 256];
  float v2 = xr[tid + 512] + p0[tid + 512] + p1[tid + 512] + bias[tid + 512];
  xr[tid] = v0; xr[tid + 256] = v1; xr[tid + 512] = v2;
  float s = v0 + v1 + v2, ss = v0 * v0 + v1 * v1 + v2 * v2;
  for (int o = 1; o < 64; o <<= 1){ s += __shfl_xor(s, o, 64); ss += __shfl_xor(ss, o, 64); }
  __shared__ float red[8];
  int w = tid >> 6, l = tid & 63;
  if (l == 0){ red[w] = s; red[w + 4] = ss; }
  __syncthreads();
  s = red[0] + red[1] + red[2] + red[3];
  ss = red[4] + red[5] + red[6] + red[7];
  float mu = s * (1.0f / Dd);
  float var = ss * (1.0f / Dd) - mu * mu;
  float rs = rsqrtf(var + 1e-5f);
  u16* yr = h + (size_t)row * Dd;
  yr[tid]       = f2bf((v0 - mu) * rs * g[tid]       + b[tid]);
  yr[tid + 256] = f2bf((v1 - mu) * rs * g[tid + 256] + b[tid + 256]);
  yr[tid + 512] = f2bf((v2 - mu) * rs * g[tid + 512] + b[tid + 512]);
}

// ---------------- transpose+convert: f32 [R][C] -> bf16 [C][R], 64r x 32c tiles ----------------
__global__ __launch_bounds__(256) void k_transpose(const float* __restrict__ src, u16* __restrict__ dst,
                                                   int R, int C, long smat, long dmat){
  __shared__ float tile[64][33];
  src += (size_t)blockIdx.z * smat;
  dst += (size_t)blockIdx.z * dmat;
  int c0 = blockIdx.x * 32, r0 = blockIdx.y * 64;
  int tid = threadIdx.x;
  int tc = tid & 31, tr = tid >> 5;
  #pragma unroll
  for (int i = 0; i < 8; i++){
    int r = tr + i * 8, c = c0 + tc;
    tile[r][tc] = (c < C) ? src[(size_t)(r0 + r) * C + c] : 0.0f;
  }
  __syncthreads();
  #pragma unroll
  for (int it = 0; it < 2; it++){
    int id = it * 256 + tid;
    int c = id & 31, rg = id >> 5, r = rg * 4;
    int cc = c0 + c;
    if (cc < C){
      s16x4 v = { (short)f2bf(tile[r][c]), (short)f2bf(tile[r + 1][c]),
                  (short)f2bf(tile[r + 2][c]), (short)f2bf(tile[r + 3][c]) };
      *(s16x4*)(dst + (size_t)cc * R + r0 + r) = v;
    }
  }
}

// ---------------- pack [bq;bk;bv] per layer into [L][2304] ----------------
__global__ void k_biaspack(const float* __restrict__ bq, const float* __restrict__ bk,
                           const float* __restrict__ bv, float* __restrict__ o){
  int i = blockIdx.x * 256 + threadIdx.x;
  int col = i % NQKV, lay = i / NQKV;
  float v = (col < Dd) ? bq[lay * Dd + col]
          : (col < 2 * Dd) ? bk[lay * Dd + col - Dd]
          : bv[lay * Dd + col - 2 * Dd];
  o[i] = v;
}

// ---------------- ring-4, 3-ahead, counted-vmcnt GEMM ----------------
// C[M=2048, N] = A * Bt^T (bf16, Bt is [N][K-stride]).
// EPI: 0 head (f32, unswapped, N-bounded, nontemporal stores)
//      1 qkv (swapped; bf16+bias+qscale; fused V-transpose)   2 ffn1 (swapped; +GELU)
//      3 wo (swapped; f32 +bias+residual in-place)            4 ffn2 split-K=2 partial
template<int BM, int BN, int EPI>
__global__ __launch_bounds__(256) void k_gemmR(const u16* __restrict__ A, const u16* __restrict__ Bt,
    const float* __restrict__ bias, float* __restrict__ Cf, u16* __restrict__ Cb,
    u16* __restrict__ vt, int Nn, int MT, int NT){
  constexpr bool SPLIT = (EPI == 4);
  constexpr int KST  = SPLIT ? Ff : Dd;
  constexpr int KLEN = SPLIT ? (Ff / 2) : Dd;
  constexpr int nk = KLEN / 32;                       // 24 or 48, divisible by 4
  constexpr int HM = BM / 2, HN = BN / 2, FM = HM / 16, FN = HN / 16;
  constexpr int nA = (BM * 4) / 256, nB = (BN * 4) / 256, NL = nA + nB;
  constexpr int ABYTE = BM * 64, BBYTE = BN * 64;     // bytes per ring slot
  __shared__ __align__(16) u16 ldsA[4 * BM * 32];
  __shared__ __align__(16) u16 ldsB[4 * BN * 32];
  int tid = threadIdx.x, wid = tid >> 6, l = tid & 63;
  int wm = wid >> 1, wn = wid & 1;
  int lr = l & 15, lc = l >> 4;
  int nwg = gridDim.x, dIdx = blockIdx.x;
  int L = (dIdx & 7) * (nwg >> 3) + (dIdx >> 3);      // XCD-chunked, nwg % 8 == 0
  int kidx = 0;
  if (SPLIT){ int per = MT * NT; kidx = L / per; L -= kidx * per; }
  int mtile = L % MT, ntile = L / MT;
  int m0 = mtile * BM, n0 = ntile * BN;
  int kbase = kidx * KLEN;

  const u16* gA[nA]; u16* dA[nA];
  const u16* gB[nB]; u16* dB[nB];
  #pragma unroll
  for (int i = 0; i < nA; i++){
    int id = i * 256 + tid, row = id >> 2, c = id & 3;
    int cs = c ^ ((row >> 1) & 3);
    gA[i] = A + (size_t)(m0 + row) * KST + kbase + cs * 8;
    dA[i] = ldsA + id * 8;
  }
  #pragma unroll
  for (int i = 0; i < nB; i++){
    int id = i * 256 + tid, row = id >> 2, c = id & 3;
    int cs = c ^ ((row >> 1) & 3);
    gB[i] = Bt + (size_t)(n0 + row) * KST + kbase + cs * 8;
    dB[i] = ldsB + id * 8;
  }
  int offA[FM], offB[FN];
  #pragma unroll
  for (int i = 0; i < FM; i++){
    int row = wm * HM + i * 16 + lr;
    offA[i] = row * 64 + ((lc ^ ((row >> 1) & 3)) << 4);
  }
  #pragma unroll
  for (int j = 0; j < FN; j++){
    int row = wn * HN + j * 16 + lr;
    offB[j] = row * 64 + ((lc ^ ((row >> 1) & 3)) << 4);
  }

  f32x4 acc[FM][FN];
  #pragma unroll
  for (int i = 0; i < FM; i++)
    #pragma unroll
    for (int j = 0; j < FN; j++) acc[i][j] = (f32x4)0.0f;

  auto stage = [&](int slot){            // slot literal at all call sites; gA/gB auto-bump
    #pragma unroll
    for (int i = 0; i < nA; i++){ gld_lds16(gA[i], (char*)dA[i] + slot * ABYTE); gA[i] += 32; }
    #pragma unroll
    for (int i = 0; i < nB; i++){ gld_lds16(gB[i], (char*)dB[i] + slot * BBYTE); gB[i] += 32; }
  };
  auto compute = [&](int slot){
    const char* bA = (const char*)ldsA + slot * ABYTE;
    const char* bB = (const char*)ldsB + slot * BBYTE;
    short8 af[FM], bfr[FN];
    #pragma unroll
    for (int i = 0; i < FM; i++) af[i] = *(const short8*)(bA + offA[i]);
    #pragma unroll
    for (int j = 0; j < FN; j++) bfr[j] = *(const short8*)(bB + offB[j]);
    asm volatile("s_waitcnt lgkmcnt(0)" ::: "memory");
    __builtin_amdgcn_sched_barrier(0);
    __builtin_amdgcn_s_setprio(1);
    #pragma unroll
    for (int i = 0; i < FM; i++)
      #pragma unroll
      for (int j = 0; j < FN; j++){
        if (EPI == 0)
          acc[i][j] = __builtin_amdgcn_mfma_f32_16x16x32_bf16(af[i], bfr[j], acc[i][j], 0, 0, 0);
        else  // swapped: lane holds one row, 4 consecutive cols
          acc[i][j] = __builtin_amdgcn_mfma_f32_16x16x32_bf16(bfr[j], af[i], acc[i][j], 0, 0, 0);
      }
    __builtin_amdgcn_s_setprio(0);
  };

  // prologue: 3 tiles in flight
  stage(0); stage(1); stage(2);
  waitv<2 * NL>(); barrier_sb();          // tile 0 landed (1,2 may fly)
  #pragma unroll 1
  for (int it = 0; it < (nk - 4) / 4; ++it){
    stage(3); compute(0); waitv<2 * NL>(); barrier_sb();
    stage(0); compute(1); waitv<2 * NL>(); barrier_sb();
    stage(1); compute(2); waitv<2 * NL>(); barrier_sb();
    stage(2); compute(3); waitv<2 * NL>(); barrier_sb();
  }
  stage(3); compute(0); waitv<2 * NL>(); barrier_sb();  // t = nk-4 (stages last tile)
  compute(1); waitv<NL>(); barrier_sb();                // t = nk-3
  compute(2); waitv<0>(); barrier_sb();                 // t = nk-2
  compute(3);                                           // t = nk-1

  if (EPI == 0){
    #pragma unroll
    for (int i = 0; i < FM; i++){
      #pragma unroll
      for (int j = 0; j < FN; j++){
        int col = n0 + wn * HN + j * 16 + lr;
        if (col >= Nn) continue;
        #pragma unroll
        for (int r = 0; r < 4; r++){
          int row = m0 + wm * HM + i * 16 + lc * 4 + r;
          __builtin_nontemporal_store(acc[i][j][r], &Cf[(size_t)row * Nn + col]);
        }
      }
    }
    return;
  }
  // swapped orientation: row = ..+lr, cols c0..c0+3
  #pragma unroll
  for (int i = 0; i < FM; i++){
    int row = m0 + wm * HM + i * 16 + lr;
    #pragma unroll
    for (int j = 0; j < FN; j++){
      int c0 = n0 + wn * HN + j * 16 + lc * 4;
      f32x4 v = acc[i][j];
      if (EPI == 4){
        *(f32x4*)(Cf + (size_t)kidx * Mtok * Dd + (size_t)row * Dd + c0) = v;
        continue;
      }
      f32x4 bv = *(const f32x4*)(bias + c0);
      v = v + bv;
      if (EPI == 3){
        f32x4* p = (f32x4*)(Cf + (size_t)row * Nn + c0);
        *p = *p + v;
        continue;
      }
      if (EPI == 1 && c0 < Dd) v = v * 0.125f;
      if (EPI == 2){
        #pragma unroll
        for (int r = 0; r < 4; r++) v[r] = 0.5f * v[r] * (1.0f + erff(v[r] * 0.70710678118f));
      }
      u16 q0 = f2bf(v[0]), q1 = f2bf(v[1]), q2 = f2bf(v[2]), q3 = f2bf(v[3]);
      if (EPI == 1 && c0 >= 2 * Dd){
        // V columns -> vt[bh][d][s] only (attn reads V from vt)
        int c2 = c0 - 2 * Dd, hh = c2 >> 6, dd2 = c2 & 63;
        int bb = row >> 10, ss2 = row & 1023;
        size_t base = ((size_t)((bb * Hh + hh) * DHh + dd2)) << 10;
        vt[base + ss2] = q0;
        vt[base + (1 << 10) + ss2] = q1;
        vt[base + (2 << 10) + ss2] = q2;
        vt[base + (3 << 10) + ss2] = q3;
      } else {
        s16x4 pv = { (short)q0, (short)q1, (short)q2, (short)q3 };
        *(s16x4*)(Cb + (size_t)row * Nn + c0) = pv;
      }
    }
  }
}

// ---------------- flash-style causal attention (swapped QK^T and PV, scalar softmax state) ----------------
// 1D grid 384 = (S/64) x (B*H), longest iq first. 4 waves; wave owns 16 q rows (q = wid*16 + lane&15).
__global__ __launch_bounds__(256) void k_attn(const u16* __restrict__ qkv, const u16* __restrict__ vt,
                                              u16* __restrict__ o){
  __shared__ __align__(16) u16 ldsK[64 * 64];
  __shared__ __align__(16) u16 ldsV[64 * 64];
  __shared__ __align__(16) u16 ldsP[4][16 * 72];   // per-wave P[q][k], row stride 72 u16
  int bid = blockIdx.x;
  int iq = (Ss / 64) - 1 - (bid / (Bbatch * Hh));  // longest first
  int bh = bid % (Bbatch * Hh);
  int b = bh / Hh, h = bh % Hh;
  int tid = threadIdx.x, wid = tid >> 6, l = tid & 63, lr = l & 15, lc = l >> 4;
  int nt = iq + 1;
  int qrow = b * Ss + iq * 64 + wid * 16 + lr;
  const u16* qp = qkv + (size_t)qrow * NQKV + h * DHh;
  short8 qf0 = *(const short8*)(qp + lc * 8);
  short8 qf1 = *(const short8*)(qp + 32 + lc * 8);

  const u16* gK[2]; const u16* gV[2]; u16* dK[2]; u16* dV[2];
  #pragma unroll
  for (int c = 0; c < 2; c++){
    int id = c * 256 + tid, row = id >> 3, ch = id & 7;
    int cs = ch ^ (row & 7);
    gK[c] = qkv + (size_t)(b * Ss + row) * NQKV + Dd + h * DHh + cs * 8;
    gV[c] = vt + ((size_t)(bh * DHh) + row) * Ss + cs * 8;
    dK[c] = ldsK + id * 8;
    dV[c] = ldsV + id * 8;
  }
  int koff[4][2];
  #pragma unroll
  for (int fn = 0; fn < 4; fn++){
    int kv = fn * 16 + lr;
    #pragma unroll
    for (int ks = 0; ks < 2; ks++){
      int ch = ks * 4 + lc;
      koff[fn][ks] = kv * 128 + ((ch ^ (kv & 7)) << 4);
    }
  }

  float mreg = -1e30f, lsum = 0.0f;
  f32x4 oacc[4];
  #pragma unroll
  for (int i = 0; i < 4; i++) oacc[i] = (f32x4)0.0f;
  u16* pbase = ldsP[wid];

  #pragma unroll 1
  for (int t = 0; t < nt; ++t){
    #pragma unroll
    for (int c = 0; c < 2; c++){ gld_lds16(gK[c], dK[c]); gK[c] += (size_t)64 * NQKV; }
    #pragma unroll
    for (int c = 0; c < 2; c++){ gld_lds16(gV[c], dV[c]); gV[c] += 64; }
    __syncthreads();
    f32x4 sc[4];
    __builtin_amdgcn_s_setprio(1);
    #pragma unroll
    for (int fn = 0; fn < 4; fn++){
      short8 kf0 = *(const short8*)((const char*)ldsK + koff[fn][0]);
      short8 kf1 = *(const short8*)((const char*)ldsK + koff[fn][1]);
      sc[fn] = __builtin_amdgcn_mfma_f32_16x16x32_bf16(kf0, qf0, (f32x4)0.0f, 0, 0, 0);
      sc[fn] = __builtin_amdgcn_mfma_f32_16x16x32_bf16(kf1, qf1, sc[fn], 0, 0, 0);
    }
    __builtin_amdgcn_s_setprio(0);
    // lane holds S[k = fn*16 + lc*4 + r][q = wid*16 + lr]
    if (t == iq){
      #pragma unroll
      for (int fn = 0; fn < 4; fn++)
        #pragma unroll
        for (int r = 0; r < 4; r++)
          if (fn * 16 + lc * 4 + r > wid * 16 + lr) sc[fn][r] = -1e30f;
    }
    float pm = sc[0][0];
    #pragma unroll
    for (int fn = 0; fn < 4; fn++)
      #pragma unroll
      for (int r = 0; r < 4; r++) pm = fmaxf(pm, sc[fn][r]);
    pm = fmaxf(pm, __shfl_xor(pm, 16, 64));
    pm = fmaxf(pm, __shfl_xor(pm, 32, 64));
    float mnew = fmaxf(mreg, pm);
    float alpha = __expf(mreg - mnew);
    mreg = mnew;
    float rs = 0.0f;
    #pragma unroll
    for (int fn = 0; fn < 4; fn++)
      #pragma unroll
      for (int r = 0; r < 4; r++){
        float p = __expf(sc[fn][r] - mnew);
        sc[fn][r] = p;
        rs += p;
      }
    rs += __shfl_xor(rs, 16, 64);
    rs += __shfl_xor(rs, 32, 64);
    lsum = lsum * alpha + rs;
    // P write: row q=lr, k = fn*16 + lc*4 + r  (4 consecutive -> s16x4)
    #pragma unroll
    for (int fn = 0; fn < 4; fn++){
      s16x4 pv = { (short)f2bf(sc[fn][0]), (short)f2bf(sc[fn][1]),
                   (short)f2bf(sc[fn][2]), (short)f2bf(sc[fn][3]) };
      *(s16x4*)((char*)pbase + lr * 144 + fn * 32 + lc * 8) = pv;
    }
    asm volatile("s_waitcnt lgkmcnt(0)" ::: "memory");
    __builtin_amdgcn_sched_barrier(0);
    #pragma unroll
    for (int fd = 0; fd < 4; fd++)
      #pragma unroll
      for (int r = 0; r < 4; r++) oacc[fd][r] *= alpha;
    short8 pa0 = *(const short8*)((const char*)pbase + lr * 144 + lc * 16);
    short8 pa1 = *(const short8*)((const char*)pbase + lr * 144 + 64 + lc * 16);
    __builtin_amdgcn_s_setprio(1);
    #pragma unroll
    for (int fd = 0; fd < 4; fd++){
      short8 vf0 = *(const short8*)((const char*)ldsV + koff[fd][0]);
      short8 vf1 = *(const short8*)((const char*)ldsV + koff[fd][1]);
      oacc[fd] = __builtin_amdgcn_mfma_f32_16x16x32_bf16(vf0, pa0, oacc[fd], 0, 0, 0);
      oacc[fd] = __builtin_amdgcn_mfma_f32_16x16x32_bf16(vf1, pa1, oacc[fd], 0, 0, 0);
    }
    __builtin_amdgcn_s_setprio(0);
    __syncthreads();
  }
  // oacc[fd][r] = O[q = wid*16+lr][d = fd*16 + lc*4 + r]
  float inv = 1.0f / lsum;
  int rowg = b * Ss + iq * 64 + wid * 16 + lr;
  #pragma unroll
  for (int fd = 0; fd < 4; fd++){
    s16x4 ov = { (short)f2bf(oacc[fd][0] * inv), (short)f2bf(oacc[fd][1] * inv),
                 (short)f2bf(oacc[fd][2] * inv), (short)f2bf(oacc[fd][3] * inv) };
    *(s16x4*)(o + (size_t)rowg * Dd + h * DHh + fd * 16 + lc * 4) = ov;
  }
}

// ---------------- host ----------------
extern "C" void kernel_launch(void* const* d_in, const int* in_sizes, int n_in,
                              void* d_out, int out_size, void* d_ws, size_t ws_size,
                              hipStream_t stream){
  const int*   ids  = (const int*)d_in[0];
  const float* tok  = (const float*)d_in[1];
  const float* pos  = (const float*)d_in[2];
  const float* Wq   = (const float*)d_in[3];
  const float* bq   = (const float*)d_in[4];
  const float* Wk   = (const float*)d_in[5];
  const float* bk   = (const float*)d_in[6];
  const float* Wv   = (const float*)d_in[7];
  const float* bv   = (const float*)d_in[8];
  const float* Wo   = (const float*)d_in[9];
  const float* bo   = (const float*)d_in[10];
  const float* ln1g = (const float*)d_in[11];
  const float* ln1b = (const float*)d_in[12];
  const float* ln2g = (const float*)d_in[13];
  const float* ln2b = (const float*)d_in[14];
  const float* W1   = (const float*)d_in[15];
  const float* b1   = (const float*)d_in[16];
  const float* W2   = (const float*)d_in[17];
  const float* b2   = (const float*)d_in[18];
  const float* lnfg = (const float*)d_in[19];
  const float* lnfb = (const float*)d_in[20];
  const float* Wh   = (const float*)d_in[21];
  float* out = (float*)d_out;

  auto al = [](size_t x){ return (x + 255) & ~(size_t)255; };
  size_t off = 0;
  auto take = [&](size_t bytes){ size_t r = off; off = al(off + bytes); return r; };
  size_t o_x    = take((size_t)Mtok * Dd * 4);
  size_t o_h    = take((size_t)Mtok * Dd * 2);
  size_t o_qkv  = take((size_t)Mtok * NQKV * 2);
  size_t o_vt   = take((size_t)Bbatch * Hh * DHh * Ss * 2);
  size_t o_o    = take((size_t)Mtok * Dd * 2);
  size_t o_mid  = take((size_t)Mtok * Ff * 2);
  size_t o_bq   = take((size_t)Ll * NQKV * 4);
  size_t o_part = take((size_t)2 * Mtok * Dd * 4);
  size_t o_rot = off;
  size_t o_wqkv, o_wo, o_w1, o_w2, o_wh;
  bool full;
  {
    size_t t = off;
    o_wqkv = t; t = al(t + (size_t)Ll * NQKV * Dd * 2);
    o_wo   = t; t = al(t + (size_t)Ll * Dd * Dd * 2);
    o_w1   = t; t = al(t + (size_t)Ll * Ff * Dd * 2);
    o_w2   = t; t = al(t + (size_t)Ll * Dd * Ff * 2);
    o_wh   = t; t = al(t + (size_t)VPAD * Dd * 2);
    full = (t <= ws_size);
  }
  char* ws = (char*)d_ws;
  float* x    = (float*)(ws + o_x);
  u16*   h    = (u16*)(ws + o_h);
  u16*   qkvb = (u16*)(ws + o_qkv);
  u16*   vtb  = (u16*)(ws + o_vt);
  u16*   ob   = (u16*)(ws + o_o);
  u16*   midb = (u16*)(ws + o_mid);
  float* bqkvp= (float*)(ws + o_bq);
  float* part = (float*)(ws + o_part);
  u16* wqkvT = full ? (u16*)(ws + o_wqkv) : (u16*)(ws + o_rot);
  u16* woT   = full ? (u16*)(ws + o_wo)   : (u16*)(ws + o_rot);
  u16* w1T   = full ? (u16*)(ws + o_w1)   : (u16*)(ws + o_rot);
  u16* w2T   = full ? (u16*)(ws + o_w2)   : (u16*)(ws + o_rot);
  u16* whT   = full ? (u16*)(ws + o_wh)   : (u16*)(ws + o_rot);

  auto tpose = [&](const float* src, u16* dst, int R, int C, int nmat, long smat, long dmat){
    k_transpose<<<dim3((C + 31) / 32, R / 64, nmat), 256, 0, stream>>>(src, dst, R, C, smat, dmat);
  };

  k_biaspack<<<(Ll * NQKV) / 256, 256, 0, stream>>>(bq, bk, bv, bqkvp);
  k_embed_ln<<<Mtok, 256, 0, stream>>>(ids, tok, pos, ln1g, ln1b, x, h);

  if (full){
    tpose(Wq, wqkvT,              Dd, Dd, Ll, (long)Dd * Dd, (long)NQKV * Dd);
    tpose(Wk, wqkvT + Dd * Dd,    Dd, Dd, Ll, (long)Dd * Dd, (long)NQKV * Dd);
    tpose(Wv, wqkvT + 2 * Dd * Dd,Dd, Dd, Ll, (long)Dd * Dd, (long)NQKV * Dd);
    tpose(Wo, woT, Dd, Dd, Ll, (long)Dd * Dd, (long)Dd * Dd);
    tpose(W1, w1T, Dd, Ff, Ll, (long)Dd * Ff, (long)Ff * Dd);
    tpose(W2, w2T, Ff, Dd, Ll, (long)Ff * Dd, (long)Dd * Ff);
    tpose(Wh, whT, Dd, Vv, 1, 0, 0);
  }

  // all grids 1D, nwg % 8 == 0
  auto gemm_qkv = [&](const u16* Aop, const u16* Bop, const float* bias, u16* Cb){
    constexpr int MT = Mtok / 64, NT = NQKV / 128;           // 576
    k_gemmR<64, 128, 1><<<MT * NT, 256, 0, stream>>>(Aop, Bop, bias, nullptr, Cb, vtb, NQKV, MT, NT);
  };
  auto gemm_wo = [&](const u16* Aop, const u16* Bop, const float* bias, float* C){
    constexpr int MT = Mtok / 64, NT = Dd / 64;              // 384
    k_gemmR<64, 64, 3><<<MT * NT, 256, 0, stream>>>(Aop, Bop, bias, C, nullptr, nullptr, Dd, MT, NT);
  };
  auto gemm_ffn1 = [&](const u16* Aop, const u16* Bop, const float* bias, u16* Cb){
    constexpr int MT = Mtok / 64, NT = Ff / 128;             // 768
    k_gemmR<64, 128, 2><<<MT * NT, 256, 0, stream>>>(Aop, Bop, bias, nullptr, Cb, nullptr, Ff, MT, NT);
  };
  auto gemm_ffn2 = [&](const u16* Aop, const u16* Bop){
    constexpr int MT = Mtok / 64, NT = Dd / 64;              // 32x12x2 = 768
    k_gemmR<64, 64, 4><<<MT * NT * 2, 256, 0, stream>>>(Aop, Bop, nullptr, part, nullptr, nullptr, Dd, MT, NT);
  };
  auto gemm_head = [&](const u16* Aop, const u16* Bop, float* C){
    constexpr int MT = Mtok / 128, NT = VPAD / 128;          // 6288
    k_gemmR<128, 128, 0><<<MT * NT, 256, 0, stream>>>(Aop, Bop, nullptr, C, nullptr, nullptr, Vv, MT, NT);
  };

  for (int l = 0; l < Ll; ++l){
    const u16* wqkvL = full ? wqkvT + (size_t)l * NQKV * Dd : wqkvT;
    const u16* woL   = full ? woT   + (size_t)l * Dd * Dd   : woT;
    const u16* w1L   = full ? w1T   + (size_t)l * Ff * Dd   : w1T;
    const u16* w2L   = full ? w2T   + (size_t)l * Dd * Ff   : w2T;
    if (!full){
      tpose(Wq + (size_t)l * Dd * Dd, wqkvT,              Dd, Dd, 1, 0, 0);
      tpose(Wk + (size_t)l * Dd * Dd, wqkvT + Dd * Dd,    Dd, Dd, 1, 0, 0);
      tpose(Wv + (size_t)l * Dd * Dd, wqkvT + 2 * Dd * Dd,Dd, Dd, 1, 0, 0);
    }
    gemm_qkv(h, wqkvL, bqkvp + l * NQKV, qkvb);
    k_attn<<<(Ss / 64) * Bbatch * Hh, 256, 0, stream>>>(qkvb, vtb, ob);
    if (!full) tpose(Wo + (size_t)l * Dd * Dd, woT, Dd, Dd, 1, 0, 0);
    gemm_wo(ob, woL, bo + l * Dd, x);
    k_ln<<<Mtok, 256, 0, stream>>>(x, ln2g + l * Dd, ln2b + l * Dd, h);
    if (!full) tpose(W1 + (size_t)l * Dd * Ff, w1T, Dd, Ff, 1, 0, 0);
    gemm_ffn1(h, w1L, b1 + l * Ff, midb);
    if (!full) tpose(W2 + (size_t)l * Ff * Dd, w2T, Ff, Dd, 1, 0, 0);
    gemm_ffn2(midb, w2L);
    const float* gN = (l + 1 < Ll) ? (ln1g + (l + 1) * Dd) : lnfg;
    const float* bN = (l + 1 < Ll) ? (ln1b + (l + 1) * Dd) : lnfb;
    k_combineln<<<Mtok, 256, 0, stream>>>(part, b2 + l * Dd, x, gN, bN, h);
  }
  if (!full) tpose(Wh, whT, Dd, Vv, 1, 0, 0);
  gemm_head(h, whT, out);
}

// Round 9
// 2092.105 us; speedup vs baseline: 1.0637x; 1.0637x over previous
//
#include <hip/hip_runtime.h>
#include <hip/hip_bf16.h>
#include <cstdint>
#include <cstddef>

#define DEV __device__ __forceinline__

typedef __attribute__((ext_vector_type(8))) short short8;   // 8 bf16 (4 VGPR)
typedef __attribute__((ext_vector_type(4))) short s16x4;
typedef __attribute__((ext_vector_type(4))) float f32x4;
typedef unsigned short u16;
typedef unsigned int u32;

static constexpr int Vv = 50257;
static constexpr int Dd = 768;
static constexpr int Ll = 12;
static constexpr int Hh = 12;
static constexpr int Ff = 3072;
static constexpr int Ss = 1024;
static constexpr int Bbatch = 2;
static constexpr int DHh = 64;
static constexpr int Mtok = Bbatch * Ss;   // 2048
static constexpr int NQKV = 3 * Dd;        // 2304
static constexpr int VPAD = 50304;         // 50257 padded to 128-multiple

DEV u16 f2bf(float f){ u32 x; __builtin_memcpy(&x, &f, 4); x += 0x7fffu + ((x >> 16) & 1u); return (u16)(x >> 16); }

DEV void gld_lds16(const void* g, void* l){
  __builtin_amdgcn_global_load_lds((const __attribute__((address_space(1))) void*)g,
                                   (__attribute__((address_space(3))) void*)l, 16, 0, 0);
}

// ---------------- fused embedding + LN1(layer0): f32 x out, bf16 h out ----------------
__global__ __launch_bounds__(256) void k_embed_ln(const int* __restrict__ ids, const float* __restrict__ tok,
                                                  const float* __restrict__ pos, const float* __restrict__ g,
                                                  const float* __restrict__ b, float* __restrict__ x,
                                                  u16* __restrict__ h){
  int t = blockIdx.x, tid = threadIdx.x;
  int id = ids[t];
  int s = t & (Ss - 1);
  const float* tr = tok + (size_t)id * Dd;
  const float* pr = pos + (size_t)s * Dd;
  float v0 = tr[tid] + pr[tid], v1 = tr[tid + 256] + pr[tid + 256], v2 = tr[tid + 512] + pr[tid + 512];
  float* xr = x + (size_t)t * Dd;
  xr[tid] = v0; xr[tid + 256] = v1; xr[tid + 512] = v2;
  float sm = v0 + v1 + v2, ss = v0 * v0 + v1 * v1 + v2 * v2;
  for (int o = 1; o < 64; o <<= 1){ sm += __shfl_xor(sm, o, 64); ss += __shfl_xor(ss, o, 64); }
  __shared__ float red[8];
  int w = tid >> 6, l = tid & 63;
  if (l == 0){ red[w] = sm; red[w + 4] = ss; }
  __syncthreads();
  sm = red[0] + red[1] + red[2] + red[3];
  ss = red[4] + red[5] + red[6] + red[7];
  float mu = sm * (1.0f / Dd);
  float var = ss * (1.0f / Dd) - mu * mu;
  float rs = rsqrtf(var + 1e-5f);
  u16* yr = h + (size_t)t * Dd;
  yr[tid]       = f2bf((v0 - mu) * rs * g[tid]       + b[tid]);
  yr[tid + 256] = f2bf((v1 - mu) * rs * g[tid + 256] + b[tid + 256]);
  yr[tid + 512] = f2bf((v2 - mu) * rs * g[tid + 512] + b[tid + 512]);
}

// ---------------- layernorm: f32 in -> bf16 out ----------------
__global__ __launch_bounds__(256) void k_ln(const float* __restrict__ x, const float* __restrict__ g,
                                            const float* __restrict__ b, u16* __restrict__ y){
  int row = blockIdx.x, tid = threadIdx.x;
  const float* xr = x + (size_t)row * Dd;
  float v0 = xr[tid], v1 = xr[tid + 256], v2 = xr[tid + 512];
  float s = v0 + v1 + v2, ss = v0 * v0 + v1 * v1 + v2 * v2;
  for (int o = 1; o < 64; o <<= 1){ s += __shfl_xor(s, o, 64); ss += __shfl_xor(ss, o, 64); }
  __shared__ float red[8];
  int w = tid >> 6, l = tid & 63;
  if (l == 0){ red[w] = s; red[w + 4] = ss; }
  __syncthreads();
  s = red[0] + red[1] + red[2] + red[3];
  ss = red[4] + red[5] + red[6] + red[7];
  float mu = s * (1.0f / Dd);
  float var = ss * (1.0f / Dd) - mu * mu;
  float rs = rsqrtf(var + 1e-5f);
  u16* yr = y + (size_t)row * Dd;
  yr[tid]       = f2bf((v0 - mu) * rs * g[tid]       + b[tid]);
  yr[tid + 256] = f2bf((v1 - mu) * rs * g[tid + 256] + b[tid + 256]);
  yr[tid + 512] = f2bf((v2 - mu) * rs * g[tid + 512] + b[tid + 512]);
}

// ---------------- fused: combine 2 split-K partials + bias + residual -> x, then LN -> h ----------------
__global__ __launch_bounds__(256) void k_combineln(const float* __restrict__ p, const float* __restrict__ bias,
                                                   float* __restrict__ x, const float* __restrict__ g,
                                                   const float* __restrict__ b, u16* __restrict__ h){
  constexpr size_t SL = (size_t)Mtok * Dd;
  int row = blockIdx.x, tid = threadIdx.x;
  float* xr = x + (size_t)row * Dd;
  const float* p0 = p + (size_t)row * Dd;
  const float* p1 = p0 + SL;
  float v0 = xr[tid]       + p0[tid]       + p1[tid]       + bias[tid];
  float v1 = xr[tid + 256] + p0[tid + 256] + p1[tid + 256] + bias[tid + 256];
  float v2 = xr[tid + 512] + p0[tid + 512] + p1[tid + 512] + bias[tid + 512];
  xr[tid] = v0; xr[tid + 256] = v1; xr[tid + 512] = v2;
  float s = v0 + v1 + v2, ss = v0 * v0 + v1 * v1 + v2 * v2;
  for (int o = 1; o < 64; o <<= 1){ s += __shfl_xor(s, o, 64); ss += __shfl_xor(ss, o, 64); }
  __shared__ float red[8];
  int w = tid >> 6, l = tid & 63;
  if (l == 0){ red[w] = s; red[w + 4] = ss; }
  __syncthreads();
  s = red[0] + red[1] + red[2] + red[3];
  ss = red[4] + red[5] + red[6] + red[7];
  float mu = s * (1.0f / Dd);
  float var = ss * (1.0f / Dd) - mu * mu;
  float rs = rsqrtf(var + 1e-5f);
  u16* yr = h + (size_t)row * Dd;
  yr[tid]       = f2bf((v0 - mu) * rs * g[tid]       + b[tid]);
  yr[tid + 256] = f2bf((v1 - mu) * rs * g[tid + 256] + b[tid + 256]);
  yr[tid + 512] = f2bf((v2 - mu) * rs * g[tid + 512] + b[tid + 512]);
}

// ---------------- transpose+convert: f32 [R][C] -> bf16 [C][R], 64r x 32c tiles ----------------
__global__ __launch_bounds__(256) void k_transpose(const float* __restrict__ src, u16* __restrict__ dst,
                                                   int R, int C, long smat, long dmat){
  __shared__ float tile[64][33];
  src += (size_t)blockIdx.z * smat;
  dst += (size_t)blockIdx.z * dmat;
  int c0 = blockIdx.x * 32, r0 = blockIdx.y * 64;
  int tid = threadIdx.x;
  int tc = tid & 31, tr = tid >> 5;
  #pragma unroll
  for (int i = 0; i < 8; i++){
    int r = tr + i * 8, c = c0 + tc;
    tile[r][tc] = (c < C) ? src[(size_t)(r0 + r) * C + c] : 0.0f;
  }
  __syncthreads();
  #pragma unroll
  for (int it = 0; it < 2; it++){
    int id = it * 256 + tid;
    int c = id & 31, rg = id >> 5, r = rg * 4;
    int cc = c0 + c;
    if (cc < C){
      s16x4 v = { (short)f2bf(tile[r][c]), (short)f2bf(tile[r + 1][c]),
                  (short)f2bf(tile[r + 2][c]), (short)f2bf(tile[r + 3][c]) };
      *(s16x4*)(dst + (size_t)cc * R + r0 + r) = v;
    }
  }
}

// ---------------- pack [bq;bk;bv] per layer into [L][2304] ----------------
__global__ void k_biaspack(const float* __restrict__ bq, const float* __restrict__ bk,
                           const float* __restrict__ bv, float* __restrict__ o){
  int i = blockIdx.x * 256 + threadIdx.x;
  int col = i % NQKV, lay = i / NQKV;
  float v = (col < Dd) ? bq[lay * Dd + col]
          : (col < 2 * Dd) ? bk[lay * Dd + col - Dd]
          : bv[lay * Dd + col - 2 * Dd];
  o[i] = v;
}

// ---------------- 2-phase double-buffered GEMM (round-6 structure) ----------------
// C[M=2048, N] = A * Bt^T (bf16, Bt is [N][K-stride]).
// EPI: 1 qkv (swapped; bf16+bias+q*log2e-scale; fused V-transpose)
//      2 ffn1 (swapped; bf16+bias+GELU)
//      3 wo (swapped; f32 +bias+residual in-place)
//      4 ffn2 split-K=2 partial (swapped; f32)
template<int BM, int BN, int EPI>
__global__ __launch_bounds__(256) void k_gemmF(const u16* __restrict__ A, const u16* __restrict__ Bt,
    const float* __restrict__ bias, float* __restrict__ Cf, u16* __restrict__ Cb,
    u16* __restrict__ vt, int Nn, int MT, int NT){
  constexpr bool SPLIT = (EPI == 4);
  constexpr int KST  = SPLIT ? Ff : Dd;
  constexpr int KLEN = SPLIT ? (Ff / 2) : Dd;
  constexpr int nk = KLEN / 32;
  constexpr int HM = BM / 2, HN = BN / 2, FM = HM / 16, FN = HN / 16;
  constexpr int nA = (BM * 4) / 256, nB = (BN * 4) / 256;
  constexpr int ABYTE = BM * 64, BBYTE = BN * 64;     // bytes per buffer
  __shared__ __align__(16) u16 ldsA[2 * BM * 32];
  __shared__ __align__(16) u16 ldsB[2 * BN * 32];
  int tid = threadIdx.x, wid = tid >> 6, l = tid & 63;
  int wm = wid >> 1, wn = wid & 1;
  int lr = l & 15, lc = l >> 4;
  int nwg = gridDim.x, dIdx = blockIdx.x;
  int L = (dIdx & 7) * (nwg >> 3) + (dIdx >> 3);      // XCD-chunked, nwg % 8 == 0
  int kidx = 0;
  if (SPLIT){ int per = MT * NT; kidx = L / per; L -= kidx * per; }
  int mtile = L % MT, ntile = L / MT;
  int m0 = mtile * BM, n0 = ntile * BN;
  int kbase = kidx * KLEN;

  const u16* gA[nA]; u16* dA[nA];
  const u16* gB[nB]; u16* dB[nB];
  #pragma unroll
  for (int i = 0; i < nA; i++){
    int id = i * 256 + tid, row = id >> 2, c = id & 3;
    int cs = c ^ ((row >> 1) & 3);
    gA[i] = A + (size_t)(m0 + row) * KST + kbase + cs * 8;
    dA[i] = ldsA + id * 8;
  }
  #pragma unroll
  for (int i = 0; i < nB; i++){
    int id = i * 256 + tid, row = id >> 2, c = id & 3;
    int cs = c ^ ((row >> 1) & 3);
    gB[i] = Bt + (size_t)(n0 + row) * KST + kbase + cs * 8;
    dB[i] = ldsB + id * 8;
  }
  int offA[FM], offB[FN];
  #pragma unroll
  for (int i = 0; i < FM; i++){
    int row = wm * HM + i * 16 + lr;
    offA[i] = row * 64 + ((lc ^ ((row >> 1) & 3)) << 4);
  }
  #pragma unroll
  for (int j = 0; j < FN; j++){
    int row = wn * HN + j * 16 + lr;
    offB[j] = row * 64 + ((lc ^ ((row >> 1) & 3)) << 4);
  }

  f32x4 acc[FM][FN];
  #pragma unroll
  for (int i = 0; i < FM; i++)
    #pragma unroll
    for (int j = 0; j < FN; j++) acc[i][j] = (f32x4)0.0f;

  auto stage = [&](int buf){
    #pragma unroll
    for (int i = 0; i < nA; i++){ gld_lds16(gA[i], (char*)dA[i] + buf * ABYTE); gA[i] += 32; }
    #pragma unroll
    for (int i = 0; i < nB; i++){ gld_lds16(gB[i], (char*)dB[i] + buf * BBYTE); gB[i] += 32; }
  };
  auto compute = [&](int buf){
    const char* bA = (const char*)ldsA + buf * ABYTE;
    const char* bB = (const char*)ldsB + buf * BBYTE;
    short8 af[FM], bfr[FN];
    #pragma unroll
    for (int i = 0; i < FM; i++) af[i] = *(const short8*)(bA + offA[i]);
    #pragma unroll
    for (int j = 0; j < FN; j++) bfr[j] = *(const short8*)(bB + offB[j]);
    #pragma unroll
    for (int i = 0; i < FM; i++)
      #pragma unroll
      for (int j = 0; j < FN; j++)
        acc[i][j] = __builtin_amdgcn_mfma_f32_16x16x32_bf16(bfr[j], af[i], acc[i][j], 0, 0, 0);
  };

  stage(0);
  __syncthreads();
  #pragma unroll 1
  for (int t = 0; t < nk - 1; ++t){
    stage((t + 1) & 1);
    compute(t & 1);
    __syncthreads();
  }
  compute((nk - 1) & 1);

  // swapped orientation: row = ..+lr, cols c0..c0+3
  #pragma unroll
  for (int i = 0; i < FM; i++){
    int row = m0 + wm * HM + i * 16 + lr;
    #pragma unroll
    for (int j = 0; j < FN; j++){
      int c0 = n0 + wn * HN + j * 16 + lc * 4;
      f32x4 v = acc[i][j];
      if (EPI == 4){
        *(f32x4*)(Cf + (size_t)kidx * Mtok * Dd + (size_t)row * Dd + c0) = v;
        continue;
      }
      f32x4 bv = *(const f32x4*)(bias + c0);
      v = v + bv;
      if (EPI == 3){
        f32x4* p = (f32x4*)(Cf + (size_t)row * Nn + c0);
        *p = *p + v;
        continue;
      }
      if (EPI == 1 && c0 < Dd) v = v * 0.18033688f;   // 0.125 * log2(e), for exp2-domain softmax
      if (EPI == 2){
        #pragma unroll
        for (int r = 0; r < 4; r++) v[r] = 0.5f * v[r] * (1.0f + erff(v[r] * 0.70710678118f));
      }
      u16 q0 = f2bf(v[0]), q1 = f2bf(v[1]), q2 = f2bf(v[2]), q3 = f2bf(v[3]);
      if (EPI == 1 && c0 >= 2 * Dd){
        // V columns -> vt[bh][d][s] only (attn reads V from vt)
        int c2 = c0 - 2 * Dd, hh = c2 >> 6, dd2 = c2 & 63;
        int bb = row >> 10, ss2 = row & 1023;
        size_t base = ((size_t)((bb * Hh + hh) * DHh + dd2)) << 10;
        vt[base + ss2] = q0;
        vt[base + (1 << 10) + ss2] = q1;
        vt[base + (2 << 10) + ss2] = q2;
        vt[base + (3 << 10) + ss2] = q3;
      } else {
        s16x4 pv = { (short)q0, (short)q1, (short)q2, (short)q3 };
        *(s16x4*)(Cb + (size_t)row * Nn + c0) = pv;
      }
    }
  }
}

// ---------------- head GEMM: 256x128 tile, 512 threads, 2-phase ----------------
__global__ __launch_bounds__(512) void k_head(const u16* __restrict__ A, const u16* __restrict__ Bt,
                                              float* __restrict__ Cf, int Nn, int MT, int NT){
  constexpr int BM = 256, BN = 128, nk = Dd / 32;
  constexpr int FM = 4, FN = 4;
  constexpr int nA = 2, nB = 1;
  constexpr int ABYTE = BM * 64, BBYTE = BN * 64;
  __shared__ __align__(16) u16 ldsA[2 * BM * 32];
  __shared__ __align__(16) u16 ldsB[2 * BN * 32];
  int tid = threadIdx.x, wid = tid >> 6, l = tid & 63;
  int wm = wid >> 1, wn = wid & 1;           // 4 x 2 waves; per-wave 64 x 64
  int lr = l & 15, lc = l >> 4;
  int nwg = gridDim.x, dIdx = blockIdx.x;
  int L = (dIdx & 7) * (nwg >> 3) + (dIdx >> 3);
  int mtile = L % MT, ntile = L / MT;
  int m0 = mtile * BM, n0 = ntile * BN;

  const u16* gA[nA]; u16* dA[nA];
  const u16* gB[nB]; u16* dB[nB];
  #pragma unroll
  for (int i = 0; i < nA; i++){
    int id = i * 512 + tid, row = id >> 2, c = id & 3;
    int cs = c ^ ((row >> 1) & 3);
    gA[i] = A + (size_t)(m0 + row) * Dd + cs * 8;
    dA[i] = ldsA + id * 8;
  }
  {
    int id = tid, row = id >> 2, c = id & 3;
    int cs = c ^ ((row >> 1) & 3);
    gB[0] = Bt + (size_t)(n0 + row) * Dd + cs * 8;
    dB[0] = ldsB + id * 8;
  }
  int offA[FM], offB[FN];
  #pragma unroll
  for (int i = 0; i < FM; i++){
    int row = wm * 64 + i * 16 + lr;
    offA[i] = row * 64 + ((lc ^ ((row >> 1) & 3)) << 4);
  }
  #pragma unroll
  for (int j = 0; j < FN; j++){
    int row = wn * 64 + j * 16 + lr;
    offB[j] = row * 64 + ((lc ^ ((row >> 1) & 3)) << 4);
  }

  f32x4 acc[FM][FN];
  #pragma unroll
  for (int i = 0; i < FM; i++)
    #pragma unroll
    for (int j = 0; j < FN; j++) acc[i][j] = (f32x4)0.0f;

  auto stage = [&](int buf){
    #pragma unroll
    for (int i = 0; i < nA; i++){ gld_lds16(gA[i], (char*)dA[i] + buf * ABYTE); gA[i] += 32; }
    gld_lds16(gB[0], (char*)dB[0] + buf * BBYTE); gB[0] += 32;
  };
  auto compute = [&](int buf){
    const char* bA = (const char*)ldsA + buf * ABYTE;
    const char* bB = (const char*)ldsB + buf * BBYTE;
    short8 af[FM], bfr[FN];
    #pragma unroll
    for (int i = 0; i < FM; i++) af[i] = *(const short8*)(bA + offA[i]);
    #pragma unroll
    for (int j = 0; j < FN; j++) bfr[j] = *(const short8*)(bB + offB[j]);
    #pragma unroll
    for (int i = 0; i < FM; i++)
      #pragma unroll
      for (int j = 0; j < FN; j++)
        acc[i][j] = __builtin_amdgcn_mfma_f32_16x16x32_bf16(af[i], bfr[j], acc[i][j], 0, 0, 0);
  };

  stage(0);
  __syncthreads();
  #pragma unroll 1
  for (int t = 0; t < nk - 1; ++t){
    stage((t + 1) & 1);
    compute(t & 1);
    __syncthreads();
  }
  compute((nk - 1) & 1);

  #pragma unroll
  for (int i = 0; i < FM; i++){
    #pragma unroll
    for (int j = 0; j < FN; j++){
      int col = n0 + wn * 64 + j * 16 + lr;
      if (col >= Nn) continue;
      #pragma unroll
      for (int r = 0; r < 4; r++){
        int row = m0 + wm * 64 + i * 16 + lc * 4 + r;
        Cf[(size_t)row * Nn + col] = acc[i][j][r];
      }
    }
  }
}

// ---------------- flash-style causal attention, KVBLK=128, exp2-domain softmax ----------------
// 1D grid 384 = (S/64) x (B*H), longest iq first. 4 waves; wave owns 16 q rows (q = wid*16 + lane&15).
__global__ __launch_bounds__(256) void k_attn(const u16* __restrict__ qkv, const u16* __restrict__ vt,
                                              u16* __restrict__ o){
  constexpr int PSTR = 272;                        // P row stride bytes (136 u16)
  __shared__ __align__(16) u16 ldsK[128 * 64];     // [k 0..127][d 0..63]
  __shared__ __align__(16) u16 ldsV[64 * 128];     // [d 0..63][s 0..127]
  __shared__ __align__(16) u16 ldsP[4][16 * 136];  // per-wave P[q][k]
  int bid = blockIdx.x;
  int iq = (Ss / 64) - 1 - (bid / (Bbatch * Hh));  // longest first
  int bh = bid % (Bbatch * Hh);
  int b = bh / Hh, h = bh % Hh;
  int tid = threadIdx.x, wid = tid >> 6, l = tid & 63, lr = l & 15, lc = l >> 4;
  int nt = (iq >> 1) + 1;                          // KV tiles of 128
  int qg = iq * 64 + wid * 16 + lr;                // global q row (within seq)
  const u16* qp = qkv + (size_t)(b * Ss + qg) * NQKV + h * DHh;
  short8 qf0 = *(const short8*)(qp + lc * 8);
  short8 qf1 = *(const short8*)(qp + 32 + lc * 8);

  // staging: K 4 chunks (128 rows x 8 chunks), V 4 chunks (64 rows x 16 chunks)
  const u16* gK[4]; const u16* gV[4]; u16* dK[4]; u16* dV[4];
  #pragma unroll
  for (int c = 0; c < 4; c++){
    int idK = c * 256 + tid, rowK = idK >> 3, chK = idK & 7;
    int csK = chK ^ (rowK & 7);
    gK[c] = qkv + (size_t)(b * Ss + rowK) * NQKV + Dd + h * DHh + csK * 8;
    dK[c] = ldsK + idK * 8;
    int idV = c * 256 + tid, rowV = idV >> 4, chV = idV & 15;
    int csV = chV ^ (rowV & 7);
    gV[c] = vt + ((size_t)(bh * DHh) + rowV) * Ss + csV * 8;
    dV[c] = ldsV + idV * 8;
  }
  int koff[8][2], voff[4][4];
  #pragma unroll
  for (int fn = 0; fn < 8; fn++){
    int kv = fn * 16 + lr;
    #pragma unroll
    for (int ks = 0; ks < 2; ks++){
      int ch = ks * 4 + lc;
      koff[fn][ks] = kv * 128 + ((ch ^ (kv & 7)) << 4);
    }
  }
  #pragma unroll
  for (int fd = 0; fd < 4; fd++){
    int dd = fd * 16 + lr;
    #pragma unroll
    for (int ks = 0; ks < 4; ks++){
      int ch = ks * 4 + lc;
      voff[fd][ks] = dd * 256 + ((ch ^ (dd & 7)) << 4);
    }
  }

  float mreg = -1e30f, lsum = 0.0f;
  f32x4 oacc[4];
  #pragma unroll
  for (int i = 0; i < 4; i++) oacc[i] = (f32x4)0.0f;
  u16* pbase = ldsP[wid];

  #pragma unroll 1
  for (int t = 0; t < nt; ++t){
    #pragma unroll
    for (int c = 0; c < 4; c++){ gld_lds16(gK[c], dK[c]); gK[c] += (size_t)128 * NQKV; }
    #pragma unroll
    for (int c = 0; c < 4; c++){ gld_lds16(gV[c], dV[c]); gV[c] += 128; }
    __syncthreads();
    f32x4 sc[8];
    __builtin_amdgcn_s_setprio(1);
    #pragma unroll
    for (int fn = 0; fn < 8; fn++){
      short8 kf0 = *(const short8*)((const char*)ldsK + koff[fn][0]);
      short8 kf1 = *(const short8*)((const char*)ldsK + koff[fn][1]);
      sc[fn] = __builtin_amdgcn_mfma_f32_16x16x32_bf16(kf0, qf0, (f32x4)0.0f, 0, 0, 0);
      sc[fn] = __builtin_amdgcn_mfma_f32_16x16x32_bf16(kf1, qf1, sc[fn], 0, 0, 0);
    }
    __builtin_amdgcn_s_setprio(0);
    // lane holds S[k = t*128 + fn*16 + lc*4 + r][q = qg]  (exp2 domain)
    if (t == nt - 1){
      #pragma unroll
      for (int fn = 0; fn < 8; fn++)
        #pragma unroll
        for (int r = 0; r < 4; r++)
          if (t * 128 + fn * 16 + lc * 4 + r > qg) sc[fn][r] = -1e30f;
    }
    float pm = sc[0][0];
    #pragma unroll
    for (int fn = 0; fn < 8; fn++)
      #pragma unroll
      for (int r = 0; r < 4; r++) pm = fmaxf(pm, sc[fn][r]);
    pm = fmaxf(pm, __shfl_xor(pm, 16, 64));
    pm = fmaxf(pm, __shfl_xor(pm, 32, 64));
    float mnew = fmaxf(mreg, pm);
    float alpha = exp2f(mreg - mnew);
    mreg = mnew;
    float rs = 0.0f;
    #pragma unroll
    for (int fn = 0; fn < 8; fn++)
      #pragma unroll
      for (int r = 0; r < 4; r++){
        float p = exp2f(sc[fn][r] - mnew);
        sc[fn][r] = p;
        rs += p;
      }
    rs += __shfl_xor(rs, 16, 64);
    rs += __shfl_xor(rs, 32, 64);
    lsum = lsum * alpha + rs;
    // P write: row q=lr, k = fn*16 + lc*4 (+r) -> s16x4
    #pragma unroll
    for (int fn = 0; fn < 8; fn++){
      s16x4 pv = { (short)f2bf(sc[fn][0]), (short)f2bf(sc[fn][1]),
                   (short)f2bf(sc[fn][2]), (short)f2bf(sc[fn][3]) };
      *(s16x4*)((char*)pbase + lr * PSTR + fn * 32 + lc * 8) = pv;
    }
    asm volatile("s_waitcnt lgkmcnt(0)" ::: "memory");
    __builtin_amdgcn_sched_barrier(0);
    #pragma unroll
    for (int fd = 0; fd < 4; fd++)
      #pragma unroll
      for (int r = 0; r < 4; r++) oacc[fd][r] *= alpha;
    short8 pa[4];
    #pragma unroll
    for (int ks = 0; ks < 4; ks++)
      pa[ks] = *(const short8*)((const char*)pbase + lr * PSTR + ks * 64 + lc * 16);
    __builtin_amdgcn_s_setprio(1);
    #pragma unroll
    for (int fd = 0; fd < 4; fd++)
      #pragma unroll
      for (int ks = 0; ks < 4; ks++){
        short8 vf = *(const short8*)((const char*)ldsV + voff[fd][ks]);
        oacc[fd] = __builtin_amdgcn_mfma_f32_16x16x32_bf16(vf, pa[ks], oacc[fd], 0, 0, 0);
      }
    __builtin_amdgcn_s_setprio(0);
    __syncthreads();
  }
  // oacc[fd][r] = O[q][d = fd*16 + lc*4 + r]
  float inv = 1.0f / lsum;
  int rowg = b * Ss + qg;
  #pragma unroll
  for (int fd = 0; fd < 4; fd++){
    s16x4 ov = { (short)f2bf(oacc[fd][0] * inv), (short)f2bf(oacc[fd][1] * inv),
                 (short)f2bf(oacc[fd][2] * inv), (short)f2bf(oacc[fd][3] * inv) };
    *(s16x4*)(o + (size_t)rowg * Dd + h * DHh + fd * 16 + lc * 4) = ov;
  }
}

// ---------------- host ----------------
extern "C" void kernel_launch(void* const* d_in, const int* in_sizes, int n_in,
                              void* d_out, int out_size, void* d_ws, size_t ws_size,
                              hipStream_t stream){
  const int*   ids  = (const int*)d_in[0];
  const float* tok  = (const float*)d_in[1];
  const float* pos  = (const float*)d_in[2];
  const float* Wq   = (const float*)d_in[3];
  const float* bq   = (const float*)d_in[4];
  const float* Wk   = (const float*)d_in[5];
  const float* bk   = (const float*)d_in[6];
  const float* Wv   = (const float*)d_in[7];
  const float* bv   = (const float*)d_in[8];
  const float* Wo   = (const float*)d_in[9];
  const float* bo   = (const float*)d_in[10];
  const float* ln1g = (const float*)d_in[11];
  const float* ln1b = (const float*)d_in[12];
  const float* ln2g = (const float*)d_in[13];
  const float* ln2b = (const float*)d_in[14];
  const float* W1   = (const float*)d_in[15];
  const float* b1   = (const float*)d_in[16];
  const float* W2   = (const float*)d_in[17];
  const float* b2   = (const float*)d_in[18];
  const float* lnfg = (const float*)d_in[19];
  const float* lnfb = (const float*)d_in[20];
  const float* Wh   = (const float*)d_in[21];
  float* out = (float*)d_out;

  auto al = [](size_t x){ return (x + 255) & ~(size_t)255; };
  size_t off = 0;
  auto take = [&](size_t bytes){ size_t r = off; off = al(off + bytes); return r; };
  size_t o_x    = take((size_t)Mtok * Dd * 4);
  size_t o_h    = take((size_t)Mtok * Dd * 2);
  size_t o_qkv  = take((size_t)Mtok * NQKV * 2);
  size_t o_vt   = take((size_t)Bbatch * Hh * DHh * Ss * 2);
  size_t o_o    = take((size_t)Mtok * Dd * 2);
  size_t o_mid  = take((size_t)Mtok * Ff * 2);
  size_t o_bq   = take((size_t)Ll * NQKV * 4);
  size_t o_part = take((size_t)2 * Mtok * Dd * 4);
  size_t o_rot = off;
  size_t o_wqkv, o_wo, o_w1, o_w2, o_wh;
  bool full;
  {
    size_t t = off;
    o_wqkv = t; t = al(t + (size_t)Ll * NQKV * Dd * 2);
    o_wo   = t; t = al(t + (size_t)Ll * Dd * Dd * 2);
    o_w1   = t; t = al(t + (size_t)Ll * Ff * Dd * 2);
    o_w2   = t; t = al(t + (size_t)Ll * Dd * Ff * 2);
    o_wh   = t; t = al(t + (size_t)VPAD * Dd * 2);
    full = (t <= ws_size);
  }
  char* ws = (char*)d_ws;
  float* x    = (float*)(ws + o_x);
  u16*   h    = (u16*)(ws + o_h);
  u16*   qkvb = (u16*)(ws + o_qkv);
  u16*   vtb  = (u16*)(ws + o_vt);
  u16*   ob   = (u16*)(ws + o_o);
  u16*   midb = (u16*)(ws + o_mid);
  float* bqkvp= (float*)(ws + o_bq);
  float* part = (float*)(ws + o_part);
  u16* wqkvT = full ? (u16*)(ws + o_wqkv) : (u16*)(ws + o_rot);
  u16* woT   = full ? (u16*)(ws + o_wo)   : (u16*)(ws + o_rot);
  u16* w1T   = full ? (u16*)(ws + o_w1)   : (u16*)(ws + o_rot);
  u16* w2T   = full ? (u16*)(ws + o_w2)   : (u16*)(ws + o_rot);
  u16* whT   = full ? (u16*)(ws + o_wh)   : (u16*)(ws + o_rot);

  auto tpose = [&](const float* src, u16* dst, int R, int C, int nmat, long smat, long dmat){
    k_transpose<<<dim3((C + 31) / 32, R / 64, nmat), 256, 0, stream>>>(src, dst, R, C, smat, dmat);
  };

  k_biaspack<<<(Ll * NQKV) / 256, 256, 0, stream>>>(bq, bk, bv, bqkvp);
  k_embed_ln<<<Mtok, 256, 0, stream>>>(ids, tok, pos, ln1g, ln1b, x, h);

  if (full){
    tpose(Wq, wqkvT,              Dd, Dd, Ll, (long)Dd * Dd, (long)NQKV * Dd);
    tpose(Wk, wqkvT + Dd * Dd,    Dd, Dd, Ll, (long)Dd * Dd, (long)NQKV * Dd);
    tpose(Wv, wqkvT + 2 * Dd * Dd,Dd, Dd, Ll, (long)Dd * Dd, (long)NQKV * Dd);
    tpose(Wo, woT, Dd, Dd, Ll, (long)Dd * Dd, (long)Dd * Dd);
    tpose(W1, w1T, Dd, Ff, Ll, (long)Dd * Ff, (long)Ff * Dd);
    tpose(W2, w2T, Ff, Dd, Ll, (long)Ff * Dd, (long)Dd * Ff);
    tpose(Wh, whT, Dd, Vv, 1, 0, 0);
  }

  // all grids 1D, nwg % 8 == 0
  auto gemm_qkv = [&](const u16* Aop, const u16* Bop, const float* bias, u16* Cb){
    constexpr int MT = Mtok / 64, NT = NQKV / 128;           // 576
    k_gemmF<64, 128, 1><<<MT * NT, 256, 0, stream>>>(Aop, Bop, bias, nullptr, Cb, vtb, NQKV, MT, NT);
  };
  auto gemm_wo = [&](const u16* Aop, const u16* Bop, const float* bias, float* C){
    constexpr int MT = Mtok / 64, NT = Dd / 64;              // 384
    k_gemmF<64, 64, 3><<<MT * NT, 256, 0, stream>>>(Aop, Bop, bias, C, nullptr, nullptr, Dd, MT, NT);
  };
  auto gemm_ffn1 = [&](const u16* Aop, const u16* Bop, const float* bias, u16* Cb){
    constexpr int MT = Mtok / 64, NT = Ff / 128;             // 768
    k_gemmF<64, 128, 2><<<MT * NT, 256, 0, stream>>>(Aop, Bop, bias, nullptr, Cb, nullptr, Ff, MT, NT);
  };
  auto gemm_ffn2 = [&](const u16* Aop, const u16* Bop){
    constexpr int MT = Mtok / 64, NT = Dd / 64;              // 32x12x2 = 768
    k_gemmF<64, 64, 4><<<MT * NT * 2, 256, 0, stream>>>(Aop, Bop, nullptr, part, nullptr, nullptr, Dd, MT, NT);
  };
  auto gemm_head = [&](const u16* Aop, const u16* Bop, float* C){
    constexpr int MT = Mtok / 256, NT = VPAD / 128;          // 8 x 393 = 3144
    k_head<<<MT * NT, 512, 0, stream>>>(Aop, Bop, C, Vv, MT, NT);
  };

  for (int l = 0; l < Ll; ++l){
    const u16* wqkvL = full ? wqkvT + (size_t)l * NQKV * Dd : wqkvT;
    const u16* woL   = full ? woT   + (size_t)l * Dd * Dd   : woT;
    const u16* w1L   = full ? w1T   + (size_t)l * Ff * Dd   : w1T;
    const u16* w2L   = full ? w2T   + (size_t)l * Dd * Ff   : w2T;
    if (!full){
      tpose(Wq + (size_t)l * Dd * Dd, wqkvT,              Dd, Dd, 1, 0, 0);
      tpose(Wk + (size_t)l * Dd * Dd, wqkvT + Dd * Dd,    Dd, Dd, 1, 0, 0);
      tpose(Wv + (size_t)l * Dd * Dd, wqkvT + 2 * Dd * Dd,Dd, Dd, 1, 0, 0);
    }
    gemm_qkv(h, wqkvL, bqkvp + l * NQKV, qkvb);
    k_attn<<<(Ss / 64) * Bbatch * Hh, 256, 0, stream>>>(qkvb, vtb, ob);
    if (!full) tpose(Wo + (size_t)l * Dd * Dd, woT, Dd, Dd, 1, 0, 0);
    gemm_wo(ob, woL, bo + l * Dd, x);
    k_ln<<<Mtok, 256, 0, stream>>>(x, ln2g + l * Dd, ln2b + l * Dd, h);
    if (!full) tpose(W1 + (size_t)l * Dd * Ff, w1T, Dd, Ff, 1, 0, 0);
    gemm_ffn1(h, w1L, b1 + l * Ff, midb);
    if (!full) tpose(W2 + (size_t)l * Ff * Dd, w2T, Ff, Dd, 1, 0, 0);
    gemm_ffn2(midb, w2L);
    const float* gN = (l + 1 < Ll) ? (ln1g + (l + 1) * Dd) : lnfg;
    const float* bN = (l + 1 < Ll) ? (ln1b + (l + 1) * Dd) : lnfb;
    k_combineln<<<Mtok, 256, 0, stream>>>(part, b2 + l * Dd, x, gN, bN, h);
  }
  if (!full) tpose(Wh, whT, Dd, Vv, 1, 0, 0);
  gemm_head(h, whT, out);
}